// Round 15
// baseline (203.848 us; speedup 1.0000x reference)
//
#include <hip/hip_runtime.h>

#define N_NODES 50000
#define N_EDGES 1600000
#define NHEAD 8
#define DH 16
#define D_IN 8
#define E_IN_DIM 12
#define HID 128
#define GRAPHS 64
#define N_PAD 50016                    // nodes rounded up to 32 for k_mlp tile loads
#define BINK 49                        // nodes per bin
#define NB 1024                        // bins (NB*BINK = 50176 >= N_NODES)
#define T_MS 8192                      // edges per msplit block
#define MSB ((N_EDGES + T_MS - 1) / T_MS)   // 196
#define LCAP 2048                      // per-bin capacity (mean 1562, sigma~40)

// ---------------- node pass 1: x = concat(pos, emb[z]);  qk[n,h,j] = scale * sum_d q[n,h,d]*Wk[j,16h+d]
__global__ __launch_bounds__(256) void k_node1(
    const float* __restrict__ pos, const int* __restrict__ z,
    const float* __restrict__ emb,
    const float* __restrict__ Wq, const float* __restrict__ Wk,
    float* __restrict__ x, float* __restrict__ qk)
{
    __shared__ float sWq[D_IN * HID];
    __shared__ float sWk[E_IN_DIM * HID];
    __shared__ float sx[32][D_IN];

    int tid = threadIdx.x;
    for (int i = tid; i < D_IN * HID; i += 256) sWq[i] = Wq[i];
    for (int i = tid; i < E_IN_DIM * HID; i += 256) sWk[i] = Wk[i];

    int nl = tid >> 3;
    int h  = tid & 7;
    int n  = blockIdx.x * 32 + nl;

    if (n < N_NODES) {
        int j = h;
        float v;
        if (j < 3) v = pos[n * 3 + j];
        else       v = emb[z[n] * 5 + (j - 3)];
        sx[nl][j] = v;
        x[n * D_IN + j] = v;
    }
    __syncthreads();
    if (n >= N_NODES) return;

    float q[DH];
    #pragma unroll
    for (int d = 0; d < DH; ++d) {
        float acc = 0.f;
        #pragma unroll
        for (int j = 0; j < D_IN; ++j)
            acc += sx[nl][j] * sWq[j * HID + h * DH + d];
        q[d] = acc;
    }
    const float scale = 0.25f;
    #pragma unroll
    for (int j = 0; j < E_IN_DIM; ++j) {
        float acc = 0.f;
        #pragma unroll
        for (int d = 0; d < DH; ++d)
            acc += q[d] * sWk[j * HID + h * DH + d];
        qk[n * 96 + h * 12 + j] = acc * scale;
    }
}

// ---------------- bin histogram: LDS-privatized 1024 counters, grid-stride
__global__ __launch_bounds__(256) void k_bhist(
    const int* __restrict__ dst, int* __restrict__ bcount)
{
    __shared__ int lh[NB];
    int tid = threadIdx.x;
    for (int i = tid; i < NB; i += 256) lh[i] = 0;
    __syncthreads();

    int stride = gridDim.x * 256;
    const int NI4 = N_EDGES / 4;
    for (int i = blockIdx.x * 256 + tid; i < NI4; i += stride) {
        int4 d4 = ((const int4*)dst)[i];
        atomicAdd(&lh[d4.x / BINK], 1);
        atomicAdd(&lh[d4.y / BINK], 1);
        atomicAdd(&lh[d4.z / BINK], 1);
        atomicAdd(&lh[d4.w / BINK], 1);
    }
    __syncthreads();
    for (int i = tid; i < NB; i += 256) {
        int v = lh[i];
        if (v > 0) atomicAdd(&bcount[i * 16], v);
    }
}

// ---------------- scan 1024 bin counts -> binoff[1025]; init bincur
__global__ __launch_bounds__(1024) void k_bscan(
    const int* __restrict__ bcount, int* __restrict__ binoff, int* __restrict__ bincur)
{
    __shared__ int tmp[NB];
    int t = threadIdx.x;
    int v = bcount[t * 16];
    tmp[t] = v;
    __syncthreads();
    #pragma unroll
    for (int off = 1; off < NB; off <<= 1) {
        int u = (t >= off) ? tmp[t - off] : 0;
        __syncthreads();
        if (t >= off) tmp[t] += u;
        __syncthreads();
    }
    int ex = tmp[t] - v;
    binoff[t] = ex;
    bincur[t * 16] = ex;
    if (t == NB - 1) binoff[NB] = tmp[t];
}

// ---------------- multisplit: ushort-perm sort in LDS, payload straight global->global
// sd packed: (src<<16)|dst (both < 65536)
__global__ __launch_bounds__(1024) void k_msplit(
    const int* __restrict__ edge_index, const float* __restrict__ edge_attr,
    int* __restrict__ bincur,
    unsigned int* __restrict__ sd_g, float4* __restrict__ ea_g)
{
    __shared__ int hist[NB];             // 4 KB
    __shared__ int hscan[NB];            // 4 KB (exclusive)
    __shared__ int cnt[NB];              // 4 KB
    __shared__ int gb[NB];               // 4 KB
    __shared__ int sdst[T_MS];           // 32 KB: cached dst window
    __shared__ unsigned short perm[T_MS];// 16 KB

    int tid = threadIdx.x;
    int base = blockIdx.x * T_MS;
    int nact = min(T_MS, N_EDGES - base);
    const int* dstp = edge_index + N_EDGES;

    for (int i = tid; i < NB; i += 1024) { hist[i] = 0; cnt[i] = 0; }
    __syncthreads();

    // pass 1: cache dst + histogram
    for (int i = tid; i < nact; i += 1024) {
        int d = dstp[base + i];
        sdst[i] = d;
        atomicAdd(&hist[d / BINK], 1);
    }
    __syncthreads();

    // scan 1024 -> exclusive hscan (in-place into hscan); reserve global ranges
    {
        int v = hist[tid];
        hscan[tid] = v;
        __syncthreads();
        #pragma unroll
        for (int off = 1; off < NB; off <<= 1) {
            int u = (tid >= off) ? hscan[tid - off] : 0;
            __syncthreads();
            if (tid >= off) hscan[tid] += u;
            __syncthreads();
        }
        int ex = hscan[tid] - v;
        gb[tid] = (v > 0) ? atomicAdd(&bincur[tid * 16], v) : 0;
        hscan[tid] = ex;
    }
    __syncthreads();

    // pass 2: rank -> perm (slot-ordered local indices)
    for (int i = tid; i < nact; i += 1024) {
        int b = sdst[i] / BINK;
        int r = atomicAdd(&cnt[b], 1);
        perm[hscan[b] + r] = (unsigned short)i;
    }
    __syncthreads();

    // pass 3: write in slot order -> coalesced runs per bin
    for (int s = tid; s < nact; s += 1024) {
        int li = (int)perm[s];
        int e = base + li;
        int d = sdst[li];
        int b = d / BINK;
        int dest = gb[b] + (s - hscan[b]);
        sd_g[dest] = ((unsigned int)edge_index[e] << 16) | (unsigned int)d;
        ea_g[dest] = ((const float4*)edge_attr)[e];
    }
}

// ---------------- fused: single-read LDS sort + wave-per-node attention (49-node bins)
__global__ __launch_bounds__(512) void k_attn_f(
    const int* __restrict__ binoff, const unsigned int* __restrict__ sd_g,
    const float4* __restrict__ ea_g,
    const float* __restrict__ x,
    const float* __restrict__ qk, const float* __restrict__ Wv,
    float* __restrict__ agg)
{
    __shared__ float sWv[E_IN_DIM * HID];       // 6 KB
    __shared__ unsigned int raw[LCAP];          // 8 KB: packed (src<<16)|dst, arrival order
    __shared__ unsigned int list[LCAP];         // 8 KB: packed (src<<16)|segIdx, node-sorted
    __shared__ int soff[BINK + 1];
    __shared__ int cnt[BINK];
    __shared__ int stmp[64];

    int tid = threadIdx.x;
    int b = blockIdx.x;
    int nlo = b * BINK;
    int nhi = min(nlo + BINK, N_NODES);
    int nn = nhi - nlo;
    if (nn <= 0) return;

    for (int i = tid; i < E_IN_DIM * HID; i += 512) sWv[i] = Wv[i];
    for (int i = tid; i < nn; i += 512) cnt[i] = 0;
    int gbeg = binoff[b];
    int total = binoff[b + 1] - gbeg;
    __syncthreads();

    // A0: single global segment read -> LDS raw + per-node histogram
    for (int i = tid; i < total; i += 512) {
        unsigned int v = sd_g[gbeg + i];
        if (i < LCAP) raw[i] = v;
        atomicAdd(&cnt[(int)(v & 0xFFFFu) - nlo], 1);
    }
    __syncthreads();

    // A1: 64-wide LDS scan -> soff
    if (tid < 64) stmp[tid] = (tid < nn) ? cnt[tid] : 0;
    __syncthreads();
    #pragma unroll
    for (int off = 1; off < 64; off <<= 1) {
        int u = 0;
        if (tid < 64 && tid >= off) u = stmp[tid - off];
        __syncthreads();
        if (tid < 64 && tid >= off) stmp[tid] += u;
        __syncthreads();
    }
    if (tid < 64) soff[tid + 1] = stmp[tid];
    if (tid == 0) soff[0] = 0;
    for (int i = tid; i < nn; i += 512) cnt[i] = 0;
    __syncthreads();

    // A2: place from LDS raw -> node-sorted list
    for (int i = tid; i < total && i < LCAP; i += 512) {
        unsigned int v = raw[i];
        int ln = (int)(v & 0xFFFFu) - nlo;
        int r = atomicAdd(&cnt[ln], 1);
        int li = soff[ln] + r;
        if (li < LCAP) list[li] = (v & 0xFFFF0000u) | (unsigned int)i;
    }
    __syncthreads();

    // B: wave-per-node attention; lane = (es = l>>3, h = l&7)
    int w = tid >> 6, l = tid & 63;
    int es = l >> 3, h = l & 7;
    const float4* easeg = ea_g + gbeg;
    for (int nl = w; nl < nn; nl += 8) {
        int n = nlo + nl;
        const float4* qr = (const float4*)(qk + (size_t)n * 96 + h * 12);
        float4 q0 = qr[0], q1 = qr[1], q2 = qr[2];
        int lbeg = soff[nl];
        int lcnt = soff[nl + 1] - lbeg;

        float sr[12];
        #pragma unroll
        for (int j = 0; j < 12; ++j) sr[j] = 0.f;
        float denom = 0.f;

        int umax = (lcnt + 7) >> 3;
        #pragma unroll 2
        for (int u = 0; u < umax; ++u) {
            int r = u * 8 + es;
            bool a2 = r < lcnt;
            unsigned int p = list[lbeg + (a2 ? r : 0)];
            int src = (int)(p >> 16);
            int seg = (int)(p & 0xFFFFu);
            const float4* xp = (const float4*)(x + src * 8);
            float4 x0 = xp[0], x1 = xp[1];
            float4 ea = easeg[seg];            // L2-resident bin segment
            float sc = x0.x*q0.x + x0.y*q0.y + x0.z*q0.z + x0.w*q0.w
                     + x1.x*q1.x + x1.y*q1.y + x1.z*q1.z + x1.w*q1.w
                     + ea.x*q2.x + ea.y*q2.y + ea.z*q2.z + ea.w*q2.w;
            float ex = a2 ? __expf(sc) : 0.f;
            denom += ex;
            sr[0] += ex * x0.x; sr[1]  += ex * x0.y; sr[2]  += ex * x0.z; sr[3]  += ex * x0.w;
            sr[4] += ex * x1.x; sr[5]  += ex * x1.y; sr[6]  += ex * x1.z; sr[7]  += ex * x1.w;
            sr[8] += ex * ea.x; sr[9]  += ex * ea.y; sr[10] += ex * ea.z; sr[11] += ex * ea.w;
        }

        #pragma unroll
        for (int m = 8; m <= 32; m <<= 1) {
            denom += __shfl_xor(denom, m);
            #pragma unroll
            for (int j = 0; j < 12; ++j) sr[j] += __shfl_xor(sr[j], m);
        }

        float inv = 1.0f / fmaxf(denom, 1e-9f);
        int d0 = h * DH + 2 * es;
        float a0 = 0.f, a1 = 0.f;
        #pragma unroll
        for (int j = 0; j < E_IN_DIM; ++j) {
            a0 += sr[j] * sWv[j * HID + d0];
            a1 += sr[j] * sWv[j * HID + d0 + 1];
        }
        *(float2*)(agg + (size_t)n * HID + d0) = make_float2(a0 * inv, a1 * inv);
    }
}

// ---------------- MLP: LDS-tiled feats = agg@Wo, relu, @lin_W, pool (LDS-bucketed atomics).
__global__ __launch_bounds__(256) void k_mlp(
    const float* __restrict__ agg, const float* __restrict__ Wo,
    const float* __restrict__ lin_W, const float* __restrict__ lin_b,
    const int* __restrict__ batch,
    float* __restrict__ gsum, float* __restrict__ gcnt)
{
    __shared__ float sWo[64 * HID];
    __shared__ float sAgg[32][HID + 1];
    __shared__ float sRed[8][33];
    __shared__ float bsum[GRAPHS];
    __shared__ int   bcnt[GRAPHS];

    int tid = threadIdx.x;
    int nbase = blockIdx.x * 32;

    if (tid < GRAPHS) { bsum[tid] = 0.f; bcnt[tid] = 0; }

    {
        const float4* ag = (const float4*)(agg + (size_t)nbase * HID);
        #pragma unroll
        for (int k = 0; k < 4; ++k) {
            int i4 = k * 256 + tid;
            float4 v = ag[i4];
            int fi = i4 * 4;
            int r = fi >> 7, c = fi & 127;
            sAgg[r][c] = v.x; sAgg[r][c + 1] = v.y; sAgg[r][c + 2] = v.z; sAgg[r][c + 3] = v.w;
        }
    }

    int h  = tid >> 5;
    int nl = tid & 31;
    int n  = nbase + nl;

    float f[16];
    #pragma unroll
    for (int d = 0; d < 16; ++d) f[d] = 0.f;

    #pragma unroll
    for (int half = 0; half < 2; ++half) {
        __syncthreads();
        const float4* wp = (const float4*)(Wo + half * 64 * HID);
        #pragma unroll
        for (int k = 0; k < 8; ++k) {
            int i4 = k * 256 + tid;
            ((float4*)sWo)[i4] = wp[i4];
        }
        __syncthreads();
        #pragma unroll 4
        for (int i = 0; i < 64; ++i) {
            float av = sAgg[nl][half * 64 + i];
            const float4* wr = (const float4*)(sWo + i * HID + h * 16);
            float4 w0 = wr[0], w1 = wr[1], w2 = wr[2], w3 = wr[3];
            f[0]  += av * w0.x; f[1]  += av * w0.y; f[2]  += av * w0.z; f[3]  += av * w0.w;
            f[4]  += av * w1.x; f[5]  += av * w1.y; f[6]  += av * w1.z; f[7]  += av * w1.w;
            f[8]  += av * w2.x; f[9]  += av * w2.y; f[10] += av * w2.z; f[11] += av * w2.w;
            f[12] += av * w3.x; f[13] += av * w3.y; f[14] += av * w3.z; f[15] += av * w3.w;
        }
    }

    const float4* lwp = (const float4*)(lin_W + h * 16);
    float4 lw0 = lwp[0], lw1 = lwp[1], lw2 = lwp[2], lw3 = lwp[3];
    float ps = fmaxf(f[0],0.f)*lw0.x + fmaxf(f[1],0.f)*lw0.y + fmaxf(f[2],0.f)*lw0.z + fmaxf(f[3],0.f)*lw0.w
             + fmaxf(f[4],0.f)*lw1.x + fmaxf(f[5],0.f)*lw1.y + fmaxf(f[6],0.f)*lw1.z + fmaxf(f[7],0.f)*lw1.w
             + fmaxf(f[8],0.f)*lw2.x + fmaxf(f[9],0.f)*lw2.y + fmaxf(f[10],0.f)*lw2.z + fmaxf(f[11],0.f)*lw2.w
             + fmaxf(f[12],0.f)*lw3.x + fmaxf(f[13],0.f)*lw3.y + fmaxf(f[14],0.f)*lw3.z + fmaxf(f[15],0.f)*lw3.w;

    sRed[h][nl] = ps;
    __syncthreads();
    if (h == 0 && n < N_NODES) {
        float y = lin_b[0];
        #pragma unroll
        for (int k = 0; k < 8; ++k) y += sRed[k][nl];
        int g = batch[n];
        atomicAdd(&bsum[g], y);
        atomicAdd(&bcnt[g], 1);
    }
    __syncthreads();
    if (tid < GRAPHS) {
        int c = bcnt[tid];
        if (c > 0) {
            atomicAdd(&gsum[tid], bsum[tid]);
            atomicAdd(&gcnt[tid], (float)c);
        }
    }
}

__global__ void k_final(const float* __restrict__ gsum, const float* __restrict__ gcnt,
                        float* __restrict__ out)
{
    int g = threadIdx.x;
    if (g < GRAPHS) out[g] = gsum[g] / fmaxf(gcnt[g], 1.0f);
}

extern "C" void kernel_launch(void* const* d_in, const int* in_sizes, int n_in,
                              void* d_out, int out_size, void* d_ws, size_t ws_size,
                              hipStream_t stream)
{
    const float* pos       = (const float*)d_in[0];
    const int*   z         = (const int*)  d_in[1];
    const int*   edge_index= (const int*)  d_in[2];
    const float* edge_attr = (const float*)d_in[3];
    const int*   batch     = (const int*)  d_in[4];
    const float* emb       = (const float*)d_in[5];
    const float* Wq        = (const float*)d_in[6];
    const float* Wk        = (const float*)d_in[7];
    const float* Wv        = (const float*)d_in[8];
    const float* Wo        = (const float*)d_in[9];
    const float* lin_W     = (const float*)d_in[10];
    const float* lin_b     = (const float*)d_in[11];
    float* out = (float*)d_out;

    // workspace layout
    char* ws = (char*)d_ws;
    float* gsum   = (float*)ws;                  // 64
    float* gcnt   = gsum + GRAPHS;               // 64
    int*   bcount = (int*)(gcnt + GRAPHS);       // 1024*16 (padded)
    int*   binoff = bcount + NB * 16;            // 1032 (1025 used, padded)
    int*   bincur = binoff + 1032;               // 1024*16 (padded)
    char*  tail   = (char*)(bincur + NB * 16);

    // zero gsum+gcnt+bcount in one shot (contiguous)
    hipMemsetAsync(gsum, 0, (size_t)(2 * GRAPHS + NB * 16) * sizeof(int), stream);

    unsigned int* sd_g = (unsigned int*)tail;          // 6.4 MB
    float4* ea_g = (float4*)(sd_g + N_EDGES);          // 25.6 MB
    float*  x    = (float*)(ea_g + N_EDGES);           // N*8 (1.6 MB)
    float*  qk   = x + (size_t)N_NODES * 8;            // N*96 (19.2 MB)
    float*  agg  = qk + (size_t)N_NODES * 96;          // N_PAD*128 (25.6 MB)

    k_node1 <<<(N_NODES + 31) / 32, 256, 0, stream>>>(pos, z, emb, Wq, Wk, x, qk);
    k_bhist <<<512, 256, 0, stream>>>(edge_index + N_EDGES, bcount);
    k_bscan <<<1, NB, 0, stream>>>(bcount, binoff, bincur);
    k_msplit<<<MSB, 1024, 0, stream>>>(edge_index, edge_attr, bincur, sd_g, ea_g);
    k_attn_f<<<NB, 512, 0, stream>>>(binoff, sd_g, ea_g, x, qk, Wv, agg);
    k_mlp   <<<(N_PAD / 32), 256, 0, stream>>>(agg, Wo, lin_W, lin_b, batch, gsum, gcnt);
    k_final <<<1, 64, 0, stream>>>(gsum, gcnt, out);
}

// Round 16
// 180.845 us; speedup vs baseline: 1.1272x; 1.1272x over previous
//
#include <hip/hip_runtime.h>

#define N_NODES 50000
#define N_EDGES 1600000
#define NHEAD 8
#define DH 16
#define D_IN 8
#define E_IN_DIM 12
#define HID 128
#define GRAPHS 64
#define N_PAD 50016                    // nodes rounded up to 32 for k_mlp tile loads
#define BINK 98                        // nodes per bin
#define NB 512                         // bins (NB*BINK = 50176 >= N_NODES)
#define T_MS 8192                      // edges per msplit block (runs of ~16/bin)
#define MSB ((N_EDGES + T_MS - 1) / T_MS)   // 196
#define LCAP 3840                      // LDS list capacity per bin (mean 3125, sigma~56)

// ---------------- node pass 1: x = concat(pos, emb[z]);  qk[n,h,j] = scale * sum_d q[n,h,d]*Wk[j,16h+d]
__global__ __launch_bounds__(256) void k_node1(
    const float* __restrict__ pos, const int* __restrict__ z,
    const float* __restrict__ emb,
    const float* __restrict__ Wq, const float* __restrict__ Wk,
    float* __restrict__ x, float* __restrict__ qk)
{
    __shared__ float sWq[D_IN * HID];
    __shared__ float sWk[E_IN_DIM * HID];
    __shared__ float sx[32][D_IN];

    int tid = threadIdx.x;
    for (int i = tid; i < D_IN * HID; i += 256) sWq[i] = Wq[i];
    for (int i = tid; i < E_IN_DIM * HID; i += 256) sWk[i] = Wk[i];

    int nl = tid >> 3;
    int h  = tid & 7;
    int n  = blockIdx.x * 32 + nl;

    if (n < N_NODES) {
        int j = h;
        float v;
        if (j < 3) v = pos[n * 3 + j];
        else       v = emb[z[n] * 5 + (j - 3)];
        sx[nl][j] = v;
        x[n * D_IN + j] = v;
    }
    __syncthreads();
    if (n >= N_NODES) return;

    float q[DH];
    #pragma unroll
    for (int d = 0; d < DH; ++d) {
        float acc = 0.f;
        #pragma unroll
        for (int j = 0; j < D_IN; ++j)
            acc += sx[nl][j] * sWq[j * HID + h * DH + d];
        q[d] = acc;
    }
    const float scale = 0.25f;
    #pragma unroll
    for (int j = 0; j < E_IN_DIM; ++j) {
        float acc = 0.f;
        #pragma unroll
        for (int d = 0; d < DH; ++d)
            acc += q[d] * sWk[j * HID + h * DH + d];
        qk[n * 96 + h * 12 + j] = acc * scale;
    }
}

// ---------------- bin histogram: LDS-privatized 512 counters, grid-stride
__global__ __launch_bounds__(256) void k_bhist(
    const int* __restrict__ dst, int* __restrict__ bcount)
{
    __shared__ int lh[NB];
    int tid = threadIdx.x;
    for (int i = tid; i < NB; i += 256) lh[i] = 0;
    __syncthreads();

    int stride = gridDim.x * 256;
    const int NI4 = N_EDGES / 4;
    for (int i = blockIdx.x * 256 + tid; i < NI4; i += stride) {
        int4 d4 = ((const int4*)dst)[i];
        atomicAdd(&lh[d4.x / BINK], 1);
        atomicAdd(&lh[d4.y / BINK], 1);
        atomicAdd(&lh[d4.z / BINK], 1);
        atomicAdd(&lh[d4.w / BINK], 1);
    }
    __syncthreads();
    for (int i = tid; i < NB; i += 256) {
        int v = lh[i];
        if (v > 0) atomicAdd(&bcount[i * 16], v);
    }
}

// ---------------- scan 512 bin counts -> binoff[513]; init bincur
__global__ __launch_bounds__(512) void k_bscan(
    const int* __restrict__ bcount, int* __restrict__ binoff, int* __restrict__ bincur)
{
    __shared__ int tmp[NB];
    int t = threadIdx.x;
    int v = bcount[t * 16];
    tmp[t] = v;
    __syncthreads();
    #pragma unroll
    for (int off = 1; off < NB; off <<= 1) {
        int u = (t >= off) ? tmp[t - off] : 0;
        __syncthreads();
        if (t >= off) tmp[t] += u;
        __syncthreads();
    }
    int ex = tmp[t] - v;
    binoff[t] = ex;
    bincur[t * 16] = ex;
    if (t == NB - 1) binoff[NB] = tmp[t];
}

// ---------------- multisplit: ushort-perm sort in LDS, payload straight global->global
// sd packed: (src<<16)|dst  (both < 65536). T_MS=8192 -> ~16-edge coalesced runs per bin.
__global__ __launch_bounds__(1024) void k_msplit(
    const int* __restrict__ edge_index, const float* __restrict__ edge_attr,
    int* __restrict__ bincur,
    unsigned int* __restrict__ sd_g, float4* __restrict__ ea_g)
{
    __shared__ int hist[NB];             // 2 KB
    __shared__ int hscan[NB];            // 2 KB (exclusive)
    __shared__ int cnt[NB];              // 2 KB
    __shared__ int gb[NB];               // 2 KB
    __shared__ int stmp[NB];             // 2 KB
    __shared__ int sdst[T_MS];           // 32 KB: cached dst window
    __shared__ unsigned short perm[T_MS];// 16 KB

    int tid = threadIdx.x;
    int base = blockIdx.x * T_MS;
    int nact = min(T_MS, N_EDGES - base);
    const int* dstp = edge_index + N_EDGES;

    for (int i = tid; i < NB; i += 1024) { hist[i] = 0; cnt[i] = 0; }
    __syncthreads();

    // pass 1: cache dst + histogram
    for (int i = tid; i < nact; i += 1024) {
        int d = dstp[base + i];
        sdst[i] = d;
        atomicAdd(&hist[d / BINK], 1);
    }
    __syncthreads();

    // scan 512 -> exclusive hscan; reserve global ranges
    if (tid < NB) stmp[tid] = hist[tid];
    __syncthreads();
    for (int off = 1; off < NB; off <<= 1) {
        int u = 0;
        if (tid < NB && tid >= off) u = stmp[tid - off];
        __syncthreads();
        if (tid < NB && tid >= off) stmp[tid] += u;
        __syncthreads();
    }
    if (tid < NB) {
        int v = hist[tid];
        hscan[tid] = stmp[tid] - v;
        gb[tid] = (v > 0) ? atomicAdd(&bincur[tid * 16], v) : 0;
    }
    __syncthreads();

    // pass 2: rank -> perm (slot-ordered local indices)
    for (int i = tid; i < nact; i += 1024) {
        int b = sdst[i] / BINK;
        int r = atomicAdd(&cnt[b], 1);
        perm[hscan[b] + r] = (unsigned short)i;
    }
    __syncthreads();

    // pass 3: write in slot order -> coalesced ~16-edge runs per bin
    for (int s = tid; s < nact; s += 1024) {
        int li = (int)perm[s];
        int e = base + li;
        int d = sdst[li];
        int b = d / BINK;
        int dest = gb[b] + (s - hscan[b]);
        sd_g[dest] = ((unsigned int)edge_index[e] << 16) | (unsigned int)d;
        ea_g[dest] = ((const float4*)edge_attr)[e];
    }
}

// ---------------- fused: single-read LDS sort + wave-per-node attention (98-node bins)
__global__ __launch_bounds__(512) void k_attn_f(
    const int* __restrict__ binoff, const unsigned int* __restrict__ sd_g,
    const float4* __restrict__ ea_g,
    const float* __restrict__ x,
    const float* __restrict__ qk, const float* __restrict__ Wv,
    float* __restrict__ agg)
{
    __shared__ float sWv[E_IN_DIM * HID];       // 6 KB
    __shared__ unsigned int raw[LCAP];          // 15 KB: packed (src<<16)|dst, arrival order
    __shared__ unsigned int list[LCAP];         // 15 KB: packed (src<<16)|segIdx, node-sorted
    __shared__ int soff[129];
    __shared__ int cnt[BINK];
    __shared__ int stmp[128];

    int tid = threadIdx.x;
    int b = blockIdx.x;
    int nlo = b * BINK;
    int nhi = min(nlo + BINK, N_NODES);
    int nn = nhi - nlo;
    if (nn <= 0) return;

    for (int i = tid; i < E_IN_DIM * HID; i += 512) sWv[i] = Wv[i];
    for (int i = tid; i < nn; i += 512) cnt[i] = 0;
    int gbeg = binoff[b];
    int total = binoff[b + 1] - gbeg;
    __syncthreads();

    // A0: single global segment read -> LDS raw + per-node histogram
    for (int i = tid; i < total; i += 512) {
        unsigned int v = sd_g[gbeg + i];
        if (i < LCAP) raw[i] = v;
        atomicAdd(&cnt[(int)(v & 0xFFFFu) - nlo], 1);
    }
    __syncthreads();

    // A1: 128-wide LDS scan -> soff
    if (tid < 128) stmp[tid] = (tid < nn) ? cnt[tid] : 0;
    __syncthreads();
    #pragma unroll
    for (int off = 1; off < 128; off <<= 1) {
        int u = 0;
        if (tid < 128 && tid >= off) u = stmp[tid - off];
        __syncthreads();
        if (tid < 128 && tid >= off) stmp[tid] += u;
        __syncthreads();
    }
    if (tid < 128) soff[tid + 1] = stmp[tid];
    if (tid == 0) soff[0] = 0;
    for (int i = tid; i < nn; i += 512) cnt[i] = 0;
    __syncthreads();

    // A2: place from LDS raw -> node-sorted list (segIdx fits 16 bits: LCAP<65536)
    for (int i = tid; i < total && i < LCAP; i += 512) {
        unsigned int v = raw[i];
        int ln = (int)(v & 0xFFFFu) - nlo;
        int r = atomicAdd(&cnt[ln], 1);
        int li = soff[ln] + r;
        if (li < LCAP) list[li] = (v & 0xFFFF0000u) | (unsigned int)i;
    }
    __syncthreads();

    // B: wave-per-node attention; lane = (es = l>>3, h = l&7)
    int w = tid >> 6, l = tid & 63;
    int es = l >> 3, h = l & 7;
    const float4* easeg = ea_g + gbeg;
    for (int nl = w; nl < nn; nl += 8) {
        int n = nlo + nl;
        const float4* qr = (const float4*)(qk + (size_t)n * 96 + h * 12);
        float4 q0 = qr[0], q1 = qr[1], q2 = qr[2];
        int lbeg = soff[nl];
        int lcnt = soff[nl + 1] - lbeg;

        float sr[12];
        #pragma unroll
        for (int j = 0; j < 12; ++j) sr[j] = 0.f;
        float denom = 0.f;

        int umax = (lcnt + 7) >> 3;
        #pragma unroll 2
        for (int u = 0; u < umax; ++u) {
            int r = u * 8 + es;
            bool a2 = r < lcnt;
            unsigned int p = list[lbeg + (a2 ? r : 0)];
            int src = (int)(p >> 16);
            int seg = (int)(p & 0xFFFFu);
            const float4* xp = (const float4*)(x + src * 8);
            float4 x0 = xp[0], x1 = xp[1];
            float4 ea = easeg[seg];            // L2-resident bin segment
            float sc = x0.x*q0.x + x0.y*q0.y + x0.z*q0.z + x0.w*q0.w
                     + x1.x*q1.x + x1.y*q1.y + x1.z*q1.z + x1.w*q1.w
                     + ea.x*q2.x + ea.y*q2.y + ea.z*q2.z + ea.w*q2.w;
            float ex = a2 ? __expf(sc) : 0.f;
            denom += ex;
            sr[0] += ex * x0.x; sr[1]  += ex * x0.y; sr[2]  += ex * x0.z; sr[3]  += ex * x0.w;
            sr[4] += ex * x1.x; sr[5]  += ex * x1.y; sr[6]  += ex * x1.z; sr[7]  += ex * x1.w;
            sr[8] += ex * ea.x; sr[9]  += ex * ea.y; sr[10] += ex * ea.z; sr[11] += ex * ea.w;
        }

        #pragma unroll
        for (int m = 8; m <= 32; m <<= 1) {
            denom += __shfl_xor(denom, m);
            #pragma unroll
            for (int j = 0; j < 12; ++j) sr[j] += __shfl_xor(sr[j], m);
        }

        float inv = 1.0f / fmaxf(denom, 1e-9f);
        int d0 = h * DH + 2 * es;
        float a0 = 0.f, a1 = 0.f;
        #pragma unroll
        for (int j = 0; j < E_IN_DIM; ++j) {
            a0 += sr[j] * sWv[j * HID + d0];
            a1 += sr[j] * sWv[j * HID + d0 + 1];
        }
        *(float2*)(agg + (size_t)n * HID + d0) = make_float2(a0 * inv, a1 * inv);
    }
}

// ---------------- MLP: LDS-tiled feats = agg@Wo, relu, @lin_W, pool (LDS-bucketed atomics).
__global__ __launch_bounds__(256) void k_mlp(
    const float* __restrict__ agg, const float* __restrict__ Wo,
    const float* __restrict__ lin_W, const float* __restrict__ lin_b,
    const int* __restrict__ batch,
    float* __restrict__ gsum, float* __restrict__ gcnt)
{
    __shared__ float sWo[64 * HID];
    __shared__ float sAgg[32][HID + 1];
    __shared__ float sRed[8][33];
    __shared__ float bsum[GRAPHS];
    __shared__ int   bcnt[GRAPHS];

    int tid = threadIdx.x;
    int nbase = blockIdx.x * 32;

    if (tid < GRAPHS) { bsum[tid] = 0.f; bcnt[tid] = 0; }

    {
        const float4* ag = (const float4*)(agg + (size_t)nbase * HID);
        #pragma unroll
        for (int k = 0; k < 4; ++k) {
            int i4 = k * 256 + tid;
            float4 v = ag[i4];
            int fi = i4 * 4;
            int r = fi >> 7, c = fi & 127;
            sAgg[r][c] = v.x; sAgg[r][c + 1] = v.y; sAgg[r][c + 2] = v.z; sAgg[r][c + 3] = v.w;
        }
    }

    int h  = tid >> 5;
    int nl = tid & 31;
    int n  = nbase + nl;

    float f[16];
    #pragma unroll
    for (int d = 0; d < 16; ++d) f[d] = 0.f;

    #pragma unroll
    for (int half = 0; half < 2; ++half) {
        __syncthreads();
        const float4* wp = (const float4*)(Wo + half * 64 * HID);
        #pragma unroll
        for (int k = 0; k < 8; ++k) {
            int i4 = k * 256 + tid;
            ((float4*)sWo)[i4] = wp[i4];
        }
        __syncthreads();
        #pragma unroll 4
        for (int i = 0; i < 64; ++i) {
            float av = sAgg[nl][half * 64 + i];
            const float4* wr = (const float4*)(sWo + i * HID + h * 16);
            float4 w0 = wr[0], w1 = wr[1], w2 = wr[2], w3 = wr[3];
            f[0]  += av * w0.x; f[1]  += av * w0.y; f[2]  += av * w0.z; f[3]  += av * w0.w;
            f[4]  += av * w1.x; f[5]  += av * w1.y; f[6]  += av * w1.z; f[7]  += av * w1.w;
            f[8]  += av * w2.x; f[9]  += av * w2.y; f[10] += av * w2.z; f[11] += av * w2.w;
            f[12] += av * w3.x; f[13] += av * w3.y; f[14] += av * w3.z; f[15] += av * w3.w;
        }
    }

    const float4* lwp = (const float4*)(lin_W + h * 16);
    float4 lw0 = lwp[0], lw1 = lwp[1], lw2 = lwp[2], lw3 = lwp[3];
    float ps = fmaxf(f[0],0.f)*lw0.x + fmaxf(f[1],0.f)*lw0.y + fmaxf(f[2],0.f)*lw0.z + fmaxf(f[3],0.f)*lw0.w
             + fmaxf(f[4],0.f)*lw1.x + fmaxf(f[5],0.f)*lw1.y + fmaxf(f[6],0.f)*lw1.z + fmaxf(f[7],0.f)*lw1.w
             + fmaxf(f[8],0.f)*lw2.x + fmaxf(f[9],0.f)*lw2.y + fmaxf(f[10],0.f)*lw2.z + fmaxf(f[11],0.f)*lw2.w
             + fmaxf(f[12],0.f)*lw3.x + fmaxf(f[13],0.f)*lw3.y + fmaxf(f[14],0.f)*lw3.z + fmaxf(f[15],0.f)*lw3.w;

    sRed[h][nl] = ps;
    __syncthreads();
    if (h == 0 && n < N_NODES) {
        float y = lin_b[0];
        #pragma unroll
        for (int k = 0; k < 8; ++k) y += sRed[k][nl];
        int g = batch[n];
        atomicAdd(&bsum[g], y);
        atomicAdd(&bcnt[g], 1);
    }
    __syncthreads();
    if (tid < GRAPHS) {
        int c = bcnt[tid];
        if (c > 0) {
            atomicAdd(&gsum[tid], bsum[tid]);
            atomicAdd(&gcnt[tid], (float)c);
        }
    }
}

__global__ void k_final(const float* __restrict__ gsum, const float* __restrict__ gcnt,
                        float* __restrict__ out)
{
    int g = threadIdx.x;
    if (g < GRAPHS) out[g] = gsum[g] / fmaxf(gcnt[g], 1.0f);
}

extern "C" void kernel_launch(void* const* d_in, const int* in_sizes, int n_in,
                              void* d_out, int out_size, void* d_ws, size_t ws_size,
                              hipStream_t stream)
{
    const float* pos       = (const float*)d_in[0];
    const int*   z         = (const int*)  d_in[1];
    const int*   edge_index= (const int*)  d_in[2];
    const float* edge_attr = (const float*)d_in[3];
    const int*   batch     = (const int*)  d_in[4];
    const float* emb       = (const float*)d_in[5];
    const float* Wq        = (const float*)d_in[6];
    const float* Wk        = (const float*)d_in[7];
    const float* Wv        = (const float*)d_in[8];
    const float* Wo        = (const float*)d_in[9];
    const float* lin_W     = (const float*)d_in[10];
    const float* lin_b     = (const float*)d_in[11];
    float* out = (float*)d_out;

    // workspace layout
    char* ws = (char*)d_ws;
    float* gsum   = (float*)ws;                  // 64
    float* gcnt   = gsum + GRAPHS;               // 64
    int*   bcount = (int*)(gcnt + GRAPHS);       // 512*16 (padded)
    int*   binoff = bcount + NB * 16;            // 520 (513 used, padded)
    int*   bincur = binoff + 520;                // 512*16 (padded)
    char*  tail   = (char*)(bincur + NB * 16);

    // zero gsum+gcnt+bcount in one shot (contiguous)
    hipMemsetAsync(gsum, 0, (size_t)(2 * GRAPHS + NB * 16) * sizeof(int), stream);

    unsigned int* sd_g = (unsigned int*)tail;          // 6.4 MB
    float4* ea_g = (float4*)(sd_g + N_EDGES);          // 25.6 MB
    float*  x    = (float*)(ea_g + N_EDGES);           // N*8 (1.6 MB)
    float*  qk   = x + (size_t)N_NODES * 8;            // N*96 (19.2 MB)
    float*  agg  = qk + (size_t)N_NODES * 96;          // N_PAD*128 (25.6 MB)

    k_node1 <<<(N_NODES + 31) / 32, 256, 0, stream>>>(pos, z, emb, Wq, Wk, x, qk);
    k_bhist <<<512, 256, 0, stream>>>(edge_index + N_EDGES, bcount);
    k_bscan <<<1, NB, 0, stream>>>(bcount, binoff, bincur);
    k_msplit<<<MSB, 1024, 0, stream>>>(edge_index, edge_attr, bincur, sd_g, ea_g);
    k_attn_f<<<NB, 512, 0, stream>>>(binoff, sd_g, ea_g, x, qk, Wv, agg);
    k_mlp   <<<(N_PAD / 32), 256, 0, stream>>>(agg, Wo, lin_W, lin_b, batch, gsum, gcnt);
    k_final <<<1, 64, 0, stream>>>(gsum, gcnt, out);
}